// Round 9
// baseline (259.777 us; speedup 1.0000x reference)
//
#include <hip/hip_runtime.h>
#include <hip/hip_fp16.h>

// ---------------------------------------------------------------------------
// 2-layer GCN on MI355X.
//   GCNConv(x) = A_hat (x W) + b = (A_hat x) W + b  (agg and linear commute),
//   and emb[labels]@W1 = (emb@W1)[labels] -> layer 1 gathers from a 256KB
//   fp16 L2-resident table; layer 2 aggregates first, then in-place GEMM.
// CSR build: ZERO global atomics (fabric atomic ceiling ~22G/s). Two-level
// counting sort (K1 hist / K2 colscan / K2b ebase / K3 scatter / K4 bsort
// with weighted-degree fold -> dinv).
// Layer-2 agg is FEATURE-CHUNKED into 4 passes of 32 columns: per-pass gather
// slice = 3.2MB < 4MB per-XCD L2 -> gathers become L2 hits (R8 showed the
// un-chunked 12.8MB footprint is random-L3 bound at ~3.5TB/s, invariant to
// MLP). out1 is stored chunk-major [4][n][32] fp16 (64B rows) by agg1.
// Wave in agg2c: 8 groups x 8 lanes; group g processes edge jstep*8+g via
// per-lane-index shfl (bpermute); lane owns 4 features (8B gather).
// dinv[src] prescale per-lane in the batch phase; temb fp16 (256B rows).
// ---------------------------------------------------------------------------

#define CHUNKS 256  // chunk = ceil(e/256) = 6250 for e=1.6M

// K1: per-chunk histogram of dst-buckets (nb = ceil(n/64) <= 1024).
__global__ __launch_bounds__(256) void hist_kernel(const int* __restrict__ dst,
                                                   int* __restrict__ hist,
                                                   int e, int chunk, int nb) {
  __shared__ unsigned lh[1024];
  int b = blockIdx.x, t = threadIdx.x;
  int start = b * chunk, end = min(e, start + chunk);
  for (int i = t; i < nb; i += 256) lh[i] = 0;
  __syncthreads();
  for (int i = start + t; i < end; i += 256) atomicAdd(&lh[dst[i] >> 6], 1u);
  __syncthreads();
  for (int k = t; k < nb; k += 256) hist[(size_t)k * CHUNKS + b] = (int)lh[k];
}

// K2: one wave per bucket k: exclusive scan of hist[k][*] over chunks.
__global__ __launch_bounds__(256) void colscan_kernel(const int* __restrict__ hist,
                                                      int* __restrict__ off,
                                                      int* __restrict__ tot,
                                                      int nb, int bact) {
  int k = (blockIdx.x * 256 + threadIdx.x) >> 6;
  int lane = threadIdx.x & 63;
  if (k >= nb) return;
  int carry = 0;
  for (int r = 0; r < CHUNKS / 64; ++r) {
    int b = r * 64 + lane;
    int h = (b < bact) ? hist[(size_t)k * CHUNKS + b] : 0;
    int x = h;
#pragma unroll
    for (int d = 1; d < 64; d <<= 1) {
      int tt = __shfl_up(x, d, 64);
      if (lane >= d) x += tt;
    }
    if (b < bact) off[(size_t)k * CHUNKS + b] = carry + x - h;
    carry += __shfl(x, 63, 64);
  }
  if (lane == 0) tot[k] = carry;
}

// K2b: single block: exclusive scan of tot[nb] -> ebase[nb+1].
__global__ __launch_bounds__(1024) void ebase_kernel(const int* __restrict__ tot,
                                                     int* __restrict__ ebase, int nb) {
  __shared__ int wsum[16];
  int t = threadIdx.x, lane = t & 63, wv = t >> 6;
  int v = (t < nb) ? tot[t] : 0;
  int x = v;
#pragma unroll
  for (int d = 1; d < 64; d <<= 1) {
    int tt = __shfl_up(x, d, 64);
    if (lane >= d) x += tt;
  }
  if (lane == 63) wsum[wv] = x;
  __syncthreads();
  int o = 0;
#pragma unroll
  for (int w = 0; w < 16; ++w) o += (w < wv) ? wsum[w] : 0;
  int excl = x - v + o;
  if (t < nb) ebase[t] = excl;
  if (t == nb - 1) ebase[nb] = excl + v;
}

// K3: scatter edges into bucket-grouped records. Rank within (chunk,bucket)
// via LDS atomic return (cumulative across batches); pos = ebase[k]+off[k][b]
// + lrank. No global atomics. rec.x = src | dst_local<<16 | label<<22.
__global__ __launch_bounds__(256) void scatter_kernel(
    const int* __restrict__ src, const int* __restrict__ dst,
    const float* __restrict__ w, const int* __restrict__ labels,
    const int* __restrict__ off, const int* __restrict__ ebase,
    int2* __restrict__ brec, int e, int chunk) {
  __shared__ unsigned bincnt[1024];
  int b = blockIdx.x, t = threadIdx.x;
  int start = b * chunk, end = min(e, start + chunk);
  for (int i = t; i < 1024; i += 256) bincnt[i] = 0;
  __syncthreads();
  for (int bs0 = start; bs0 < end; bs0 += 1792) {
    int bend = min(end, bs0 + 1792);
    int s[7], d[7], lb[7], ps[7];
    float wv[7];
#pragma unroll
    for (int u = 0; u < 7; ++u) {
      int i = bs0 + u * 256 + t;
      bool ok = i < bend;
      s[u] = ok ? src[i] : 0;
      d[u] = ok ? dst[i] : 0;
      wv[u] = ok ? w[i] : 0.f;
    }
#pragma unroll
    for (int u = 0; u < 7; ++u) lb[u] = labels[s[u]];
#pragma unroll
    for (int u = 0; u < 7; ++u) {
      int k = d[u] >> 6;
      ps[u] = ebase[k] + off[(size_t)k * CHUNKS + b];
    }
#pragma unroll
    for (int u = 0; u < 7; ++u) {
      int i = bs0 + u * 256 + t;
      if (i < bend) {
        int k = d[u] >> 6;
        unsigned lr = atomicAdd(&bincnt[k], 1u);
        unsigned rx = (unsigned)s[u] | ((unsigned)(d[u] & 63) << 16) |
                      ((unsigned)lb[u] << 22);
        brec[ps[u] + (int)lr] = make_int2((int)rx, __float_as_int(wv[u]));
      }
    }
  }
}

// K4: per-bucket 64-bin sort: brec -> csr (src|label<<16, w), plus rs[] and
// dinv (weighted-degree fold: rsum via LDS float atomics on the first pass).
__global__ __launch_bounds__(256) void bsort_kernel(const int2* __restrict__ brec,
                                                    const int* __restrict__ ebase,
                                                    int2* __restrict__ csr,
                                                    int* __restrict__ rs,
                                                    float* __restrict__ dinv, int n) {
  __shared__ unsigned h64[64];
  __shared__ unsigned cur[64];
  __shared__ float rsum[64];
  int k = blockIdx.x, t = threadIdx.x;
  int e0 = ebase[k], e1 = ebase[k + 1];
  if (t < 64) { h64[t] = 0; rsum[t] = 0.f; }
  __syncthreads();
  for (int i = e0 + t; i < e1; i += 256) {
    int2 r = brec[i];
    unsigned dl = ((unsigned)r.x >> 16) & 63u;
    atomicAdd(&h64[dl], 1u);
    atomicAdd(&rsum[dl], __int_as_float(r.y));
  }
  __syncthreads();
  if (t < 64) {
    int hv = (int)h64[t];
    int x = hv;
#pragma unroll
    for (int d = 1; d < 64; d <<= 1) {
      int tt = __shfl_up(x, d, 64);
      if (t >= d) x += tt;
    }
    int ex = x - hv;
    cur[t] = (unsigned)(e0 + ex);
    int v = k * 64 + t;
    if (v <= n) rs[v] = e0 + ex;  // last bucket's lane localN writes rs[n]=e
    if (v < n) dinv[v] = rsqrtf(1.0f + rsum[t]);
  }
  __syncthreads();
  for (int i = e0 + t; i < e1; i += 256) {
    int2 r = brec[i];
    unsigned rx = (unsigned)r.x;
    int dl = (int)((rx >> 16) & 63u);
    int pos = (int)atomicAdd(&cur[dl], 1u);
    csr[pos] = make_int2((int)((rx & 0xffffu) | ((rx >> 22) << 16)), r.y);
  }
}

// temb = emb_table @ W1, stored fp16  (vocab x 128) -- 256KB L2-resident table
__global__ void temb_kernel(const float* __restrict__ emb, const float* __restrict__ W1,
                            __half* __restrict__ temb) {
  int r = blockIdx.x, j = threadIdx.x;
  __shared__ float xs[128];
  xs[j] = emb[r * 128 + j];
  __syncthreads();
  float acc = 0.f;
#pragma unroll 8
  for (int k = 0; k < 128; ++k) acc = fmaf(xs[k], W1[k * 128 + j], acc);
  temb[r * 128 + j] = __float2half_rn(acc);
}

// unpack 4 halves (loaded as float2, 8B) -> two float2
__device__ __forceinline__ void unpack4(float2 raw, float2& a, float2& b) {
  union { float f; __half2 h; } u0, u1;
  u0.f = raw.x;
  u1.f = raw.y;
  a = __half22float2(u0.h);
  b = __half22float2(u1.h);
}

// Layer 1: out1 = relu(A_hat temb[labels] + b1), fp16 in; CHUNK-MAJOR fp16
// out: out1c[c][n][32], c = col/32. Pair-gather (2x32 lanes, 4 feat/lane).
__global__ __launch_bounds__(256) void agg1_kernel(
    const int* __restrict__ rs, const int2* __restrict__ csr,
    const float* __restrict__ dinv, const int* __restrict__ labels,
    const __half* __restrict__ temb, const float* __restrict__ b1,
    __half* __restrict__ out1c, int n) {
  int wid = (blockIdx.x * blockDim.x + threadIdx.x) >> 6;
  int lane = threadIdx.x & 63;
  if (wid >= n) return;
  int half = lane >> 5, fl = lane & 31;
  float di = dinv[wid];
  float acc0, acc1, acc2, acc3;
  {
    int selfrow = labels[wid];
    float2 raw = ((const float2*)(temb + (size_t)selfrow * 128))[fl];
    float2 a, b;
    unpack4(raw, a, b);
    float ss = half ? 0.f : di;  // self term once (half 0 only)
    acc0 = a.x * ss; acc1 = a.y * ss; acc2 = b.x * ss; acc3 = b.y * ss;
  }
  int r1v = rs[wid + 1];
  for (int base = rs[wid]; base < r1v; base += 64) {
    int s = 0;
    float v = 0.f;
    if (base + lane < r1v) {
      int2 c = csr[base + lane];
      s = c.x;
      v = __int_as_float(c.y) * dinv[c.x & 0xffff];
    }
    int nb = min(64, r1v - base);
    int j = 0;
    for (; j + 16 <= nb; j += 16) {
#pragma unroll
      for (int u = 0; u < 8; ++u) {
        int jj = j + 2 * u + half;
        int sj = __shfl(s, jj, 64);
        float vj = __shfl(v, jj, 64);
        float2 raw = ((const float2*)(temb + (size_t)(sj >> 16) * 128))[fl];
        float2 a, b;
        unpack4(raw, a, b);
        acc0 = fmaf(a.x, vj, acc0); acc1 = fmaf(a.y, vj, acc1);
        acc2 = fmaf(b.x, vj, acc2); acc3 = fmaf(b.y, vj, acc3);
      }
    }
    for (; j + 2 <= nb; j += 2) {
      int jj = j + half;
      int sj = __shfl(s, jj, 64);
      float vj = __shfl(v, jj, 64);
      float2 raw = ((const float2*)(temb + (size_t)(sj >> 16) * 128))[fl];
      float2 a, b;
      unpack4(raw, a, b);
      acc0 = fmaf(a.x, vj, acc0); acc1 = fmaf(a.y, vj, acc1);
      acc2 = fmaf(b.x, vj, acc2); acc3 = fmaf(b.y, vj, acc3);
    }
    if (j < nb) {  // leftover single edge: half 1 contributes 0
      int sj = __shfl(s, j, 64);
      float vj0 = __shfl(v, j, 64);
      float vj = half ? 0.f : vj0;
      float2 raw = ((const float2*)(temb + (size_t)(sj >> 16) * 128))[fl];
      float2 a, b;
      unpack4(raw, a, b);
      acc0 = fmaf(a.x, vj, acc0); acc1 = fmaf(a.y, vj, acc1);
      acc2 = fmaf(b.x, vj, acc2); acc3 = fmaf(b.y, vj, acc3);
    }
  }
  acc0 += __shfl_xor(acc0, 32, 64);
  acc1 += __shfl_xor(acc1, 32, 64);
  acc2 += __shfl_xor(acc2, 32, 64);
  acc3 += __shfl_xor(acc3, 32, 64);
  if (half == 0) {
    float4 b4 = ((const float4*)b1)[fl];
    acc0 = fmaxf(fmaf(acc0, di, b4.x), 0.f);
    acc1 = fmaxf(fmaf(acc1, di, b4.y), 0.f);
    acc2 = fmaxf(fmaf(acc2, di, b4.z), 0.f);
    acc3 = fmaxf(fmaf(acc3, di, b4.w), 0.f);
    union { float2 f2; __half2 h2[2]; } o;
    o.h2[0] = __float22half2_rn(make_float2(acc0, acc1));
    o.h2[1] = __float22half2_rn(make_float2(acc2, acc3));
    // chunk-major: chunk = fl>>3, within-chunk float2 index = fl&7
    ((float2*)(out1c + (((size_t)(fl >> 3) * n + wid) * 32)))[fl & 7] = o.f2;
  }
}

// Layer 2 aggregation, feature-chunked: out[:, 32c..32c+31] = A_hat h_c,
// h_c = 3.2MB fp16 slice [n][32] (L2-resident). Wave = 8 groups x 8 lanes;
// group g handles edge jstep*8+g (per-lane-index shfl); lane owns 4 features.
__global__ __launch_bounds__(256) void agg2c_kernel(
    const int* __restrict__ rs, const int2* __restrict__ csr,
    const float* __restrict__ dinv, const __half* __restrict__ hc,
    float* __restrict__ out, int n, int c) {
  int wid = (blockIdx.x * blockDim.x + threadIdx.x) >> 6;
  int lane = threadIdx.x & 63;
  if (wid >= n) return;
  int grp = lane >> 3, fl = lane & 7;
  float di = dinv[wid];
  float acc0 = 0.f, acc1 = 0.f, acc2 = 0.f, acc3 = 0.f;
  if (grp == 0) {  // self term (counted once)
    float2 raw = ((const float2*)(hc + (size_t)wid * 32))[fl];
    float2 a, b;
    unpack4(raw, a, b);
    acc0 = a.x * di; acc1 = a.y * di; acc2 = b.x * di; acc3 = b.y * di;
  }
  int r1v = rs[wid + 1];
  for (int base = rs[wid]; base < r1v; base += 64) {
    int s = 0;
    float v = 0.f;  // lanes past the end hold s=0,v=0 -> contribute 0
    if (base + lane < r1v) {
      int2 cc = csr[base + lane];
      s = cc.x;
      v = __int_as_float(cc.y) * dinv[cc.x & 0xffff];
    }
    int nb = min(64, r1v - base);
#pragma unroll
    for (int jstep = 0; jstep < 8; ++jstep) {
      if (jstep * 8 < nb) {  // wave-uniform predicate
        int j = jstep * 8 + grp;
        int sj = __shfl(s, j, 64);
        float vj = __shfl(v, j, 64);
        float2 raw = ((const float2*)(hc + (size_t)(sj & 0xffff) * 32))[fl];
        float2 a, b;
        unpack4(raw, a, b);
        acc0 = fmaf(a.x, vj, acc0); acc1 = fmaf(a.y, vj, acc1);
        acc2 = fmaf(b.x, vj, acc2); acc3 = fmaf(b.y, vj, acc3);
      }
    }
  }
  // reduce across the 8 groups
  acc0 += __shfl_xor(acc0, 8, 64);  acc1 += __shfl_xor(acc1, 8, 64);
  acc2 += __shfl_xor(acc2, 8, 64);  acc3 += __shfl_xor(acc3, 8, 64);
  acc0 += __shfl_xor(acc0, 16, 64); acc1 += __shfl_xor(acc1, 16, 64);
  acc2 += __shfl_xor(acc2, 16, 64); acc3 += __shfl_xor(acc3, 16, 64);
  acc0 += __shfl_xor(acc0, 32, 64); acc1 += __shfl_xor(acc1, 32, 64);
  acc2 += __shfl_xor(acc2, 32, 64); acc3 += __shfl_xor(acc3, 32, 64);
  if (grp == 0) {
    ((float4*)(out + (size_t)wid * 128 + 32 * c))[fl] =
        make_float4(acc0 * di, acc1 * di, acc2 * di, acc3 * di);
  }
}

// In-place: y[rb..rb+31] = y[rb..rb+31] @ W + b. Each block only touches its
// own 32 rows (staged to LDS before overwrite) -> in-place safe.
__global__ __launch_bounds__(256) void gemm_bias_kernel(float* __restrict__ y,
                                                        const float* __restrict__ W,
                                                        const float* __restrict__ bias,
                                                        int n) {
  __shared__ float xs[32][128];
  int tid = threadIdx.x;
  int tc = tid & 31;
  int tr = tid >> 5;
  int rb = blockIdx.x * 32;
  {
    const float4* xg = (const float4*)(y + (size_t)rb * 128);
    float4* xls = (float4*)&xs[0][0];
#pragma unroll
    for (int i = 0; i < 4; ++i) {
      int idx = tid + i * 256;  // float4 index; row = idx>>5
      int row = rb + (idx >> 5);
      float4 val = (row < n) ? xg[idx] : make_float4(0.f, 0.f, 0.f, 0.f);
      xls[idx] = val;
    }
  }
  __syncthreads();
  int j0 = tc * 4;
  float4 b4 = *(const float4*)(bias + j0);
  float acc[4][4];
#pragma unroll
  for (int r = 0; r < 4; ++r) {
    acc[r][0] = b4.x; acc[r][1] = b4.y; acc[r][2] = b4.z; acc[r][3] = b4.w;
  }
#pragma unroll 4
  for (int k = 0; k < 128; ++k) {
    float4 w4 = *(const float4*)(W + k * 128 + j0);
#pragma unroll
    for (int r = 0; r < 4; ++r) {
      float xv = xs[tr * 4 + r][k];
      acc[r][0] = fmaf(xv, w4.x, acc[r][0]);
      acc[r][1] = fmaf(xv, w4.y, acc[r][1]);
      acc[r][2] = fmaf(xv, w4.z, acc[r][2]);
      acc[r][3] = fmaf(xv, w4.w, acc[r][3]);
    }
  }
#pragma unroll
  for (int r = 0; r < 4; ++r) {
    int row = rb + tr * 4 + r;
    if (row < n)
      *(float4*)(y + (size_t)row * 128 + j0) =
          make_float4(acc[r][0], acc[r][1], acc[r][2], acc[r][3]);
  }
}

extern "C" void kernel_launch(void* const* d_in, const int* in_sizes, int n_in,
                              void* d_out, int out_size, void* d_ws, size_t ws_size,
                              hipStream_t stream) {
  const int* labels = (const int*)d_in[0];
  const int* edge_index = (const int*)d_in[1];
  const float* weight = (const float*)d_in[2];
  const float* emb = (const float*)d_in[3];
  const float* W1 = (const float*)d_in[4];
  const float* b1 = (const float*)d_in[5];
  const float* W2 = (const float*)d_in[6];
  const float* b2 = (const float*)d_in[7];

  int n = in_sizes[0];
  int e = in_sizes[1] / 2;
  int vocab = in_sizes[3] / 128;
  const int* srcp = edge_index;
  const int* dstp = edge_index + e;

  int nb = (n + 63) >> 6;                 // dst buckets (782)
  int chunk = (e + CHUNKS - 1) / CHUNKS;  // 6250
  int bact = (e + chunk - 1) / chunk;     // actual chunks (<= CHUNKS)

  // workspace carve-up (float elements, 256-aligned). Total ~42 MiB.
  float* ws = (float*)d_ws;
  size_t o = 0;
  auto alloc_f = [&](size_t c) { float* p = ws + o; o += (c + 255) & ~(size_t)255; return p; };
  int*    hist  = (int*)alloc_f((size_t)nb * CHUNKS);
  int*    off   = (int*)alloc_f((size_t)nb * CHUNKS);
  int*    tot   = (int*)alloc_f(nb);
  int*    ebase = (int*)alloc_f(nb + 1);
  int2*   brec  = (int2*)alloc_f((size_t)e * 2);
  int*    rs    = (int*)alloc_f(n + 1);
  int2*   csr   = (int2*)alloc_f((size_t)e * 2);
  float*  dinv  = alloc_f(n);
  __half* temb  = (__half*)alloc_f((size_t)vocab * 64);  // vocab*128 halves
  __half* out1c = (__half*)alloc_f((size_t)n * 64);      // [4][n][32] halves
  (void)ws_size;

  dim3 b256(256);
  int gagg = (int)(((size_t)n * 64 + 255) / 256);

  hist_kernel<<<bact, b256, 0, stream>>>(dstp, hist, e, chunk, nb);
  colscan_kernel<<<(nb * 64 + 255) / 256, b256, 0, stream>>>(hist, off, tot, nb, bact);
  ebase_kernel<<<1, 1024, 0, stream>>>(tot, ebase, nb);
  scatter_kernel<<<bact, b256, 0, stream>>>(srcp, dstp, weight, labels, off, ebase,
                                            brec, e, chunk);
  bsort_kernel<<<nb, b256, 0, stream>>>(brec, ebase, csr, rs, dinv, n);
  temb_kernel<<<vocab, 128, 0, stream>>>(emb, W1, temb);
  // layer 1: out1c = relu(A_hat temb[labels] + b1)  (fp16, chunk-major)
  agg1_kernel<<<gagg, b256, 0, stream>>>(rs, csr, dinv, labels, temb, b1, out1c, n);
  // layer 2: d_out = (A_hat out1) @ W2 + b2 -- 4 L2-resident column passes,
  // then in-place GEMM
  for (int c = 0; c < 4; ++c) {
    agg2c_kernel<<<gagg, b256, 0, stream>>>(rs, csr, dinv,
                                            out1c + (size_t)c * n * 32,
                                            (float*)d_out, n, c);
  }
  gemm_bias_kernel<<<(n + 31) / 32, b256, 0, stream>>>((float*)d_out, W2, b2, n);
}

// Round 10
// 186.135 us; speedup vs baseline: 1.3956x; 1.3956x over previous
//
#include <hip/hip_runtime.h>
#include <hip/hip_fp16.h>

// ---------------------------------------------------------------------------
// 2-layer GCN on MI355X.
//   GCNConv(x) = A_hat (x W) + b = (A_hat x) W + b  (agg and linear commute),
//   and emb[labels]@W1 = (emb@W1)[labels] -> layer 1 gathers from a 256KB
//   fp16 L2-resident table; layer 2 aggregates first, then in-place GEMM.
// CSR build: ZERO global atomics (fabric atomic ceiling ~22G/s). Two-level
// counting sort (K1 hist / K2 colscan / K2b ebase / K3 scatter / K4 bsort
// with weighted-degree fold -> dinv). K1/K3 use 1024-thread blocks (16
// waves/CU -- they are latency-bound; 256-thread blocks gave only 4 waves/CU).
// K3 precomputes gbase[k] in LDS; K4 stages the bucket in LDS (1 brec read).
// R9 lesson: aggs are at an instruction-issue floor (~5.5 wave-instr/edge),
// NOT cache-bound (L2-resident agg1 ~= L3-random agg2) -> keep R8 agg shape:
// pair-gather, batch-64 edge records, shfl-broadcast, dinv[src] per-lane in
// the batch phase; out1/temb fp16 (256B rows).
// ---------------------------------------------------------------------------

#define CHUNKS 256  // chunk = ceil(e/256) = 6250 for e=1.6M
#define BSTAGE 2816 // bucket stage entries (avg bucket = 2048, 5sigma ~ 2300)

// K1: per-chunk histogram of dst-buckets (nb = ceil(n/64) <= 1024).
__global__ __launch_bounds__(1024) void hist_kernel(const int* __restrict__ dst,
                                                    int* __restrict__ hist,
                                                    int e, int chunk, int nb) {
  __shared__ unsigned lh[1024];
  int b = blockIdx.x, t = threadIdx.x;
  lh[t] = 0;
  __syncthreads();
  int start = b * chunk, end = min(e, start + chunk);
  for (int i = start + t; i < end; i += 1024) atomicAdd(&lh[dst[i] >> 6], 1u);
  __syncthreads();
  if (t < nb) hist[(size_t)t * CHUNKS + b] = (int)lh[t];
}

// K2: one wave per bucket k: exclusive scan of hist[k][*] over chunks.
__global__ __launch_bounds__(256) void colscan_kernel(const int* __restrict__ hist,
                                                      int* __restrict__ off,
                                                      int* __restrict__ tot,
                                                      int nb, int bact) {
  int k = (blockIdx.x * 256 + threadIdx.x) >> 6;
  int lane = threadIdx.x & 63;
  if (k >= nb) return;
  int carry = 0;
  for (int r = 0; r < CHUNKS / 64; ++r) {
    int b = r * 64 + lane;
    int h = (b < bact) ? hist[(size_t)k * CHUNKS + b] : 0;
    int x = h;
#pragma unroll
    for (int d = 1; d < 64; d <<= 1) {
      int tt = __shfl_up(x, d, 64);
      if (lane >= d) x += tt;
    }
    if (b < bact) off[(size_t)k * CHUNKS + b] = carry + x - h;
    carry += __shfl(x, 63, 64);
  }
  if (lane == 0) tot[k] = carry;
}

// K2b: single block: exclusive scan of tot[nb] -> ebase[nb+1].
__global__ __launch_bounds__(1024) void ebase_kernel(const int* __restrict__ tot,
                                                     int* __restrict__ ebase, int nb) {
  __shared__ int wsum[16];
  int t = threadIdx.x, lane = t & 63, wv = t >> 6;
  int v = (t < nb) ? tot[t] : 0;
  int x = v;
#pragma unroll
  for (int d = 1; d < 64; d <<= 1) {
    int tt = __shfl_up(x, d, 64);
    if (lane >= d) x += tt;
  }
  if (lane == 63) wsum[wv] = x;
  __syncthreads();
  int o = 0;
#pragma unroll
  for (int w = 0; w < 16; ++w) o += (w < wv) ? wsum[w] : 0;
  int excl = x - v + o;
  if (t < nb) ebase[t] = excl;
  if (t == nb - 1) ebase[nb] = excl + v;
}

// K3: scatter edges into bucket-grouped records. Rank within (chunk,bucket)
// via LDS atomic return; pos = gbase[k] + lrank (gbase precomputed in LDS).
// No global atomics. rec.x = src | dst_local<<16 | label<<22.
__global__ __launch_bounds__(1024) void scatter_kernel(
    const int* __restrict__ src, const int* __restrict__ dst,
    const float* __restrict__ w, const int* __restrict__ labels,
    const int* __restrict__ off, const int* __restrict__ ebase,
    int2* __restrict__ brec, int e, int chunk, int nb) {
  __shared__ unsigned bincnt[1024];
  __shared__ int gbase[1024];
  int b = blockIdx.x, t = threadIdx.x;
  bincnt[t] = 0;
  if (t < nb) gbase[t] = ebase[t] + off[(size_t)t * CHUNKS + b];
  __syncthreads();
  int start = b * chunk, end = min(e, start + chunk);
  int s[7], d[7], lb[7], ps[7];
  float wv[7];
#pragma unroll
  for (int u = 0; u < 7; ++u) {
    int i = start + u * 1024 + t;
    bool ok = i < end;
    s[u] = ok ? src[i] : 0;
    d[u] = ok ? dst[i] : 0;
    wv[u] = ok ? w[i] : 0.f;
  }
#pragma unroll
  for (int u = 0; u < 7; ++u) lb[u] = labels[s[u]];
#pragma unroll
  for (int u = 0; u < 7; ++u) ps[u] = gbase[d[u] >> 6];
#pragma unroll
  for (int u = 0; u < 7; ++u) {
    int i = start + u * 1024 + t;
    if (i < end) {
      int k = d[u] >> 6;
      unsigned lr = atomicAdd(&bincnt[k], 1u);
      unsigned rx = (unsigned)s[u] | ((unsigned)(d[u] & 63) << 16) |
                    ((unsigned)lb[u] << 22);
      brec[ps[u] + (int)lr] = make_int2((int)rx, __float_as_int(wv[u]));
    }
  }
}

// K4: per-bucket 64-bin sort: brec -> csr (src|label<<16, w), plus rs[] and
// dinv (weighted-degree fold). Bucket staged in LDS -> brec read ONCE.
__global__ __launch_bounds__(256) void bsort_kernel(const int2* __restrict__ brec,
                                                    const int* __restrict__ ebase,
                                                    int2* __restrict__ csr,
                                                    int* __restrict__ rs,
                                                    float* __restrict__ dinv, int n) {
  __shared__ int2 stage[BSTAGE];
  __shared__ unsigned h64[64];
  __shared__ unsigned cur[64];
  __shared__ float rsum[64];
  int k = blockIdx.x, t = threadIdx.x;
  int e0 = ebase[k], e1 = ebase[k + 1], cnt = e1 - e0;
  if (t < 64) { h64[t] = 0; rsum[t] = 0.f; }
  __syncthreads();
  bool fits = (cnt <= BSTAGE);
  for (int i = t; i < cnt; i += 256) {
    int2 r = brec[e0 + i];
    if (fits) stage[i] = r;
    unsigned dl = ((unsigned)r.x >> 16) & 63u;
    atomicAdd(&h64[dl], 1u);
    atomicAdd(&rsum[dl], __int_as_float(r.y));
  }
  __syncthreads();
  if (t < 64) {
    int hv = (int)h64[t];
    int x = hv;
#pragma unroll
    for (int d = 1; d < 64; d <<= 1) {
      int tt = __shfl_up(x, d, 64);
      if (t >= d) x += tt;
    }
    int ex = x - hv;
    cur[t] = (unsigned)(e0 + ex);
    int v = k * 64 + t;
    if (v <= n) rs[v] = e0 + ex;  // last bucket's lane localN writes rs[n]=e
    if (v < n) dinv[v] = rsqrtf(1.0f + rsum[t]);
  }
  __syncthreads();
  for (int i = t; i < cnt; i += 256) {
    int2 r = fits ? stage[i] : brec[e0 + i];
    unsigned rx = (unsigned)r.x;
    int dl = (int)((rx >> 16) & 63u);
    int pos = (int)atomicAdd(&cur[dl], 1u);
    csr[pos] = make_int2((int)((rx & 0xffffu) | ((rx >> 22) << 16)), r.y);
  }
}

// temb = emb_table @ W1, stored fp16  (vocab x 128) -- 256KB L2-resident table
__global__ void temb_kernel(const float* __restrict__ emb, const float* __restrict__ W1,
                            __half* __restrict__ temb) {
  int r = blockIdx.x, j = threadIdx.x;
  __shared__ float xs[128];
  xs[j] = emb[r * 128 + j];
  __syncthreads();
  float acc = 0.f;
#pragma unroll 8
  for (int k = 0; k < 128; ++k) acc = fmaf(xs[k], W1[k * 128 + j], acc);
  temb[r * 128 + j] = __float2half_rn(acc);
}

// unpack 4 halves (loaded as float2, 8B) -> two float2
__device__ __forceinline__ void unpack4(float2 raw, float2& a, float2& b) {
  union { float f; __half2 h; } u0, u1;
  u0.f = raw.x;
  u1.f = raw.y;
  a = __half22float2(u0.h);
  b = __half22float2(u1.h);
}

// Layer 1: out1 = relu(A_hat temb[labels] + b1), fp16 in/out. Pair-gather:
// half = lane>>5 handles edges j+half; lane owns features 4*fl..4*fl+3.
__global__ __launch_bounds__(256) void agg1_kernel(
    const int* __restrict__ rs, const int2* __restrict__ csr,
    const float* __restrict__ dinv, const int* __restrict__ labels,
    const __half* __restrict__ temb, const float* __restrict__ b1,
    __half* __restrict__ out1, int n) {
  int wid = (blockIdx.x * blockDim.x + threadIdx.x) >> 6;
  int lane = threadIdx.x & 63;
  if (wid >= n) return;
  int half = lane >> 5, fl = lane & 31;
  float di = dinv[wid];
  float acc0, acc1, acc2, acc3;
  {
    int selfrow = labels[wid];
    float2 raw = ((const float2*)(temb + (size_t)selfrow * 128))[fl];
    float2 a, b;
    unpack4(raw, a, b);
    float ss = half ? 0.f : di;  // self term once (half 0 only)
    acc0 = a.x * ss; acc1 = a.y * ss; acc2 = b.x * ss; acc3 = b.y * ss;
  }
  int r1v = rs[wid + 1];
  for (int base = rs[wid]; base < r1v; base += 64) {
    int s = 0;
    float v = 0.f;
    if (base + lane < r1v) {
      int2 c = csr[base + lane];
      s = c.x;
      v = __int_as_float(c.y) * dinv[c.x & 0xffff];
    }
    int nb = min(64, r1v - base);
    int j = 0;
    for (; j + 16 <= nb; j += 16) {
#pragma unroll
      for (int u = 0; u < 8; ++u) {
        int jj = j + 2 * u + half;
        int sj = __shfl(s, jj, 64);
        float vj = __shfl(v, jj, 64);
        float2 raw = ((const float2*)(temb + (size_t)(sj >> 16) * 128))[fl];
        float2 a, b;
        unpack4(raw, a, b);
        acc0 = fmaf(a.x, vj, acc0); acc1 = fmaf(a.y, vj, acc1);
        acc2 = fmaf(b.x, vj, acc2); acc3 = fmaf(b.y, vj, acc3);
      }
    }
    for (; j + 2 <= nb; j += 2) {
      int jj = j + half;
      int sj = __shfl(s, jj, 64);
      float vj = __shfl(v, jj, 64);
      float2 raw = ((const float2*)(temb + (size_t)(sj >> 16) * 128))[fl];
      float2 a, b;
      unpack4(raw, a, b);
      acc0 = fmaf(a.x, vj, acc0); acc1 = fmaf(a.y, vj, acc1);
      acc2 = fmaf(b.x, vj, acc2); acc3 = fmaf(b.y, vj, acc3);
    }
    if (j < nb) {  // leftover single edge: half 1 contributes 0
      int sj = __shfl(s, j, 64);
      float vj0 = __shfl(v, j, 64);
      float vj = half ? 0.f : vj0;
      float2 raw = ((const float2*)(temb + (size_t)(sj >> 16) * 128))[fl];
      float2 a, b;
      unpack4(raw, a, b);
      acc0 = fmaf(a.x, vj, acc0); acc1 = fmaf(a.y, vj, acc1);
      acc2 = fmaf(b.x, vj, acc2); acc3 = fmaf(b.y, vj, acc3);
    }
  }
  acc0 += __shfl_xor(acc0, 32, 64);
  acc1 += __shfl_xor(acc1, 32, 64);
  acc2 += __shfl_xor(acc2, 32, 64);
  acc3 += __shfl_xor(acc3, 32, 64);
  if (half == 0) {
    float4 b4 = ((const float4*)b1)[fl];
    acc0 = fmaxf(fmaf(acc0, di, b4.x), 0.f);
    acc1 = fmaxf(fmaf(acc1, di, b4.y), 0.f);
    acc2 = fmaxf(fmaf(acc2, di, b4.z), 0.f);
    acc3 = fmaxf(fmaf(acc3, di, b4.w), 0.f);
    union { float2 f2; __half2 h2[2]; } o;
    o.h2[0] = __float22half2_rn(make_float2(acc0, acc1));
    o.h2[1] = __float22half2_rn(make_float2(acc2, acc3));
    ((float2*)(out1 + (size_t)wid * 128))[fl] = o.f2;
  }
}

// Layer 2 aggregation: out = A_hat h (fp16 gather source, f32 output).
// Same pair-gather structure.
__global__ __launch_bounds__(256) void agg2_kernel(
    const int* __restrict__ rs, const int2* __restrict__ csr,
    const float* __restrict__ dinv, const __half* __restrict__ h,
    float* __restrict__ out, int n) {
  int wid = (blockIdx.x * blockDim.x + threadIdx.x) >> 6;
  int lane = threadIdx.x & 63;
  if (wid >= n) return;
  int half = lane >> 5, fl = lane & 31;
  float di = dinv[wid];
  float acc0, acc1, acc2, acc3;
  {
    float2 raw = ((const float2*)(h + (size_t)wid * 128))[fl];
    float2 a, b;
    unpack4(raw, a, b);
    float ss = half ? 0.f : di;
    acc0 = a.x * ss; acc1 = a.y * ss; acc2 = b.x * ss; acc3 = b.y * ss;
  }
  int r1v = rs[wid + 1];
  for (int base = rs[wid]; base < r1v; base += 64) {
    int s = 0;
    float v = 0.f;
    if (base + lane < r1v) {
      int2 c = csr[base + lane];
      s = c.x;
      v = __int_as_float(c.y) * dinv[c.x & 0xffff];
    }
    int nb = min(64, r1v - base);
    int j = 0;
    for (; j + 16 <= nb; j += 16) {
#pragma unroll
      for (int u = 0; u < 8; ++u) {
        int jj = j + 2 * u + half;
        int sj = __shfl(s, jj, 64);
        float vj = __shfl(v, jj, 64);
        float2 raw = ((const float2*)(h + (size_t)(sj & 0xffff) * 128))[fl];
        float2 a, b;
        unpack4(raw, a, b);
        acc0 = fmaf(a.x, vj, acc0); acc1 = fmaf(a.y, vj, acc1);
        acc2 = fmaf(b.x, vj, acc2); acc3 = fmaf(b.y, vj, acc3);
      }
    }
    for (; j + 2 <= nb; j += 2) {
      int jj = j + half;
      int sj = __shfl(s, jj, 64);
      float vj = __shfl(v, jj, 64);
      float2 raw = ((const float2*)(h + (size_t)(sj & 0xffff) * 128))[fl];
      float2 a, b;
      unpack4(raw, a, b);
      acc0 = fmaf(a.x, vj, acc0); acc1 = fmaf(a.y, vj, acc1);
      acc2 = fmaf(b.x, vj, acc2); acc3 = fmaf(b.y, vj, acc3);
    }
    if (j < nb) {
      int sj = __shfl(s, j, 64);
      float vj0 = __shfl(v, j, 64);
      float vj = half ? 0.f : vj0;
      float2 raw = ((const float2*)(h + (size_t)(sj & 0xffff) * 128))[fl];
      float2 a, b;
      unpack4(raw, a, b);
      acc0 = fmaf(a.x, vj, acc0); acc1 = fmaf(a.y, vj, acc1);
      acc2 = fmaf(b.x, vj, acc2); acc3 = fmaf(b.y, vj, acc3);
    }
  }
  acc0 += __shfl_xor(acc0, 32, 64);
  acc1 += __shfl_xor(acc1, 32, 64);
  acc2 += __shfl_xor(acc2, 32, 64);
  acc3 += __shfl_xor(acc3, 32, 64);
  if (half == 0) {
    ((float4*)(out + (size_t)wid * 128))[fl] =
        make_float4(acc0 * di, acc1 * di, acc2 * di, acc3 * di);
  }
}

// In-place: y[rb..rb+31] = y[rb..rb+31] @ W + b. Each block only touches its
// own 32 rows (staged to LDS before overwrite) -> in-place safe.
__global__ __launch_bounds__(256) void gemm_bias_kernel(float* __restrict__ y,
                                                        const float* __restrict__ W,
                                                        const float* __restrict__ bias,
                                                        int n) {
  __shared__ float xs[32][128];
  int tid = threadIdx.x;
  int tc = tid & 31;
  int tr = tid >> 5;
  int rb = blockIdx.x * 32;
  {
    const float4* xg = (const float4*)(y + (size_t)rb * 128);
    float4* xls = (float4*)&xs[0][0];
#pragma unroll
    for (int i = 0; i < 4; ++i) {
      int idx = tid + i * 256;  // float4 index; row = idx>>5
      int row = rb + (idx >> 5);
      float4 val = (row < n) ? xg[idx] : make_float4(0.f, 0.f, 0.f, 0.f);
      xls[idx] = val;
    }
  }
  __syncthreads();
  int j0 = tc * 4;
  float4 b4 = *(const float4*)(bias + j0);
  float acc[4][4];
#pragma unroll
  for (int r = 0; r < 4; ++r) {
    acc[r][0] = b4.x; acc[r][1] = b4.y; acc[r][2] = b4.z; acc[r][3] = b4.w;
  }
#pragma unroll 4
  for (int k = 0; k < 128; ++k) {
    float4 w4 = *(const float4*)(W + k * 128 + j0);
#pragma unroll
    for (int r = 0; r < 4; ++r) {
      float xv = xs[tr * 4 + r][k];
      acc[r][0] = fmaf(xv, w4.x, acc[r][0]);
      acc[r][1] = fmaf(xv, w4.y, acc[r][1]);
      acc[r][2] = fmaf(xv, w4.z, acc[r][2]);
      acc[r][3] = fmaf(xv, w4.w, acc[r][3]);
    }
  }
#pragma unroll
  for (int r = 0; r < 4; ++r) {
    int row = rb + tr * 4 + r;
    if (row < n)
      *(float4*)(y + (size_t)row * 128 + j0) =
          make_float4(acc[r][0], acc[r][1], acc[r][2], acc[r][3]);
  }
}

extern "C" void kernel_launch(void* const* d_in, const int* in_sizes, int n_in,
                              void* d_out, int out_size, void* d_ws, size_t ws_size,
                              hipStream_t stream) {
  const int* labels = (const int*)d_in[0];
  const int* edge_index = (const int*)d_in[1];
  const float* weight = (const float*)d_in[2];
  const float* emb = (const float*)d_in[3];
  const float* W1 = (const float*)d_in[4];
  const float* b1 = (const float*)d_in[5];
  const float* W2 = (const float*)d_in[6];
  const float* b2 = (const float*)d_in[7];

  int n = in_sizes[0];
  int e = in_sizes[1] / 2;
  int vocab = in_sizes[3] / 128;
  const int* srcp = edge_index;
  const int* dstp = edge_index + e;

  int nb = (n + 63) >> 6;                 // dst buckets (782)
  int chunk = (e + CHUNKS - 1) / CHUNKS;  // 6250 (<= 7*1024 for scatter staging)
  int bact = (e + chunk - 1) / chunk;     // actual chunks (<= CHUNKS)

  // workspace carve-up (float elements, 256-aligned). Total ~42 MiB.
  float* ws = (float*)d_ws;
  size_t o = 0;
  auto alloc_f = [&](size_t c) { float* p = ws + o; o += (c + 255) & ~(size_t)255; return p; };
  int*    hist  = (int*)alloc_f((size_t)nb * CHUNKS);
  int*    off   = (int*)alloc_f((size_t)nb * CHUNKS);
  int*    tot   = (int*)alloc_f(nb);
  int*    ebase = (int*)alloc_f(nb + 1);
  int2*   brec  = (int2*)alloc_f((size_t)e * 2);
  int*    rs    = (int*)alloc_f(n + 1);
  int2*   csr   = (int2*)alloc_f((size_t)e * 2);
  float*  dinv  = alloc_f(n);
  __half* temb  = (__half*)alloc_f((size_t)vocab * 64);  // vocab*128 halves
  __half* out1  = (__half*)alloc_f((size_t)n * 64);      // n*128 halves
  (void)ws_size;

  dim3 b256(256);
  dim3 b1024(1024);
  int gagg = (int)(((size_t)n * 64 + 255) / 256);

  hist_kernel<<<bact, b1024, 0, stream>>>(dstp, hist, e, chunk, nb);
  colscan_kernel<<<(nb * 64 + 255) / 256, b256, 0, stream>>>(hist, off, tot, nb, bact);
  ebase_kernel<<<1, b1024, 0, stream>>>(tot, ebase, nb);
  scatter_kernel<<<bact, b1024, 0, stream>>>(srcp, dstp, weight, labels, off, ebase,
                                             brec, e, chunk, nb);
  bsort_kernel<<<nb, b256, 0, stream>>>(brec, ebase, csr, rs, dinv, n);
  temb_kernel<<<vocab, 128, 0, stream>>>(emb, W1, temb);
  // layer 1: out1 = relu(A_hat temb[labels] + b1)  (fp16 in/out)
  agg1_kernel<<<gagg, b256, 0, stream>>>(rs, csr, dinv, labels, temb, b1, out1, n);
  // layer 2: d_out = (A_hat out1) @ W2 + b2   (agg first, then in-place GEMM)
  agg2_kernel<<<gagg, b256, 0, stream>>>(rs, csr, dinv, out1, (float*)d_out, n);
  gemm_bias_kernel<<<(n + 31) / 32, b256, 0, stream>>>((float*)d_out, W2, b2, n);
}